// Round 7
// baseline (289.614 us; speedup 1.0000x reference)
//
#include <hip/hip_runtime.h>
#include <hip/hip_bf16.h>
#include <hip/hip_fp8.h>

#define NR 8192
#define DIM 512

typedef __attribute__((ext_vector_type(4))) int   i32x4;
typedef __attribute__((ext_vector_type(8))) int   i32x8;
typedef __attribute__((ext_vector_type(4))) float f32x4;

__device__ static inline void gload_lds16(const void* g, void* l) {
    __builtin_amdgcn_global_load_lds(
        (const __attribute__((address_space(1))) void*)g,
        (__attribute__((address_space(3))) void*)l, 16, 0, 0);
}

// One block (256 threads) per row: compute |im|^2, |s|^2, im.s in one pass,
// write fp8(e4m3)-normalized rows + fp32 diag (diag stays EXACT fp32 — it is
// subtracted from every term; fp8 error only enters scores, which the loss
// is linear in). Block 0 zeroes the accumulator.
__global__ __launch_bounds__(256) void normalize_kernel(
    const float* __restrict__ im, const float* __restrict__ s,
    unsigned char* __restrict__ im_q, unsigned char* __restrict__ s_q,
    float* __restrict__ diag, double* __restrict__ acc)
{
    const int row = blockIdx.x;
    const int t = threadIdx.x;
    if (row == 0 && t == 0) acc[0] = 0.0;

    const float2* imr = (const float2*)(im + (size_t)row * DIM);
    const float2* sr  = (const float2*)(s  + (size_t)row * DIM);
    float2 iv = imr[t];
    float2 sv = sr[t];

    float sim = iv.x * iv.x + iv.y * iv.y;
    float sss = sv.x * sv.x + sv.y * sv.y;
    float sd  = iv.x * sv.x + iv.y * sv.y;

    #pragma unroll
    for (int off = 32; off; off >>= 1) {
        sim += __shfl_down(sim, off);
        sss += __shfl_down(sss, off);
        sd  += __shfl_down(sd, off);
    }

    __shared__ float red[3][4];
    const int wid = t >> 6, lane = t & 63;
    if (lane == 0) { red[0][wid] = sim; red[1][wid] = sss; red[2][wid] = sd; }
    __syncthreads();
    sim = red[0][0] + red[0][1] + red[0][2] + red[0][3];
    sss = red[1][0] + red[1][1] + red[1][2] + red[1][3];
    sd  = red[2][0] + red[2][1] + red[2][2] + red[2][3];

    const float ri = rsqrtf(sim);
    const float rs = rsqrtf(sss);
    if (t == 0) diag[row] = sd * ri * rs;

    __hip_fp8_e4m3 qa0(iv.x * ri), qa1(iv.y * ri);
    __hip_fp8_e4m3 qb0(sv.x * rs), qb1(sv.y * rs);
    unsigned short ua = (unsigned short)qa0.__x | ((unsigned short)qa1.__x << 8);
    unsigned short ub = (unsigned short)qb0.__x | ((unsigned short)qb1.__x << 8);
    ((unsigned short*)(im_q + (size_t)row * DIM))[t] = ua;
    ((unsigned short*)(s_q  + (size_t)row * DIM))[t] = ub;
}

// 256x256 tile, BK=128 (fp8), 8 waves (2M x 4N), double-buffered LDS 128 KiB.
// R3-verified pipeline ported to MX-fp8: 4 K-windows (DIM/128), 4 phases per
// window {ds_reads + stage half-tile -> vmcnt(4)[+lgkm(8)] -> s_barrier ->
// lgkmcnt(0)+sched_barrier -> setprio(1) 8 x mfma_scale_16x16x128 setprio(0)
// -> s_barrier}. vmcnt never 0 in main loop (R3 ledger: each drain targets
// loads issued 2 phases earlier). Unit e8m0 scales (127) — no scale traffic.
// LDS rows are 128 B (= BK fp8), same XOR chunk swizzle as R3 (2-way = free).
__global__ __launch_bounds__(512, 2) void gemm_loss_kernel(
    const unsigned char* __restrict__ A,
    const unsigned char* __restrict__ B,
    const float* __restrict__ diag,
    double* __restrict__ acc_out)
{
    __shared__ char Asm[2][32768];   // [buf][256 rows][128 B]
    __shared__ char Bsm[2][32768];

    const int tid  = threadIdx.x;
    const int l    = tid & 63;
    const int w    = tid >> 6;          // wave 0..7
    const int wm   = w >> 2;            // 0..1
    const int wn   = w & 3;             // 0..3
    const int bm = blockIdx.y, bn = blockIdx.x;

    const int lr = l >> 3;              // 0..7 row within 8-row group
    const int ls = l & 7;               // 0..7 16B slot
    const int csw = ls ^ lr;            // swizzled content chunk for staging

    const int frow = l & 15;            // fragment lane row (output row/col)
    const int fc   = l >> 4;            // 0..3: 32-byte K-slice index

    const char* Agb = (const char*)A + (size_t)bm * 256 * DIM;
    const char* Bgb = (const char*)B + (size_t)bn * 256 * DIM;

    auto stageA = [&](int b, int h, int tt) {
        #pragma unroll
        for (int q = 0; q < 2; ++q) {
            const int rit = h * 128 + q * 64 + w * 8 + lr;
            gload_lds16(Agb + (size_t)rit * DIM + tt * 128 + csw * 16,
                        &Asm[b][(h * 128 + q * 64 + w * 8) * 128]);
        }
    };
    auto stageB = [&](int b, int h, int tt) {
        #pragma unroll
        for (int q = 0; q < 2; ++q) {
            const int rit = h * 128 + q * 64 + w * 8 + lr;
            gload_lds16(Bgb + (size_t)rit * DIM + tt * 128 + csw * 16,
                        &Bsm[b][(h * 128 + q * 64 + w * 8) * 128]);
        }
    };

    // fragment: lane reads its 32-byte K-slice (two swizzled 16B slots)
    auto ldA = [&](i32x8 (&af)[4], int b, int qm) {
        #pragma unroll
        for (int mi = 0; mi < 4; ++mi) {
            const int row = qm * 128 + wm * 64 + mi * 16 + frow;
            const int rsw = (row & 7) << 4;
            i32x4 lo = *(const i32x4*)&Asm[b][row * 128 + (((fc * 2    ) << 4) ^ rsw)];
            i32x4 hi = *(const i32x4*)&Asm[b][row * 128 + (((fc * 2 + 1) << 4) ^ rsw)];
            af[mi] = __builtin_shufflevector(lo, hi, 0, 1, 2, 3, 4, 5, 6, 7);
        }
    };
    auto ldB = [&](i32x8 (&bfr)[2], int b, int qn) {
        #pragma unroll
        for (int ni = 0; ni < 2; ++ni) {
            const int row = qn * 128 + wn * 32 + ni * 16 + frow;
            const int rsw = (row & 7) << 4;
            i32x4 lo = *(const i32x4*)&Bsm[b][row * 128 + (((fc * 2    ) << 4) ^ rsw)];
            i32x4 hi = *(const i32x4*)&Bsm[b][row * 128 + (((fc * 2 + 1) << 4) ^ rsw)];
            bfr[ni] = __builtin_shufflevector(lo, hi, 0, 1, 2, 3, 4, 5, 6, 7);
        }
    };

    f32x4 acc00[4][2], acc01[4][2], acc11[4][2], acc10[4][2];
    f32x4 zero = {0.f, 0.f, 0.f, 0.f};
    #pragma unroll
    for (int mi = 0; mi < 4; ++mi)
        #pragma unroll
        for (int ni = 0; ni < 2; ++ni) {
            acc00[mi][ni] = zero; acc01[mi][ni] = zero;
            acc11[mi][ni] = zero; acc10[mi][ni] = zero;
        }

    auto mmaq = [&](f32x4 (&ac)[4][2], i32x8 (&af)[4], i32x8 (&bfr)[2]) {
        __builtin_amdgcn_s_setprio(1);
        #pragma unroll
        for (int mi = 0; mi < 4; ++mi)
            #pragma unroll
            for (int ni = 0; ni < 2; ++ni)
                ac[mi][ni] = __builtin_amdgcn_mfma_scale_f32_16x16x128_f8f6f4(
                    af[mi], bfr[ni], ac[mi][ni],
                    0, 0,          // cbsz=fp8(e4m3), blgp=fp8(e4m3)
                    0, 127,        // scale_a opsel, scale_a = e8m0 1.0
                    0, 127);       // scale_b opsel, scale_b = e8m0 1.0
        __builtin_amdgcn_s_setprio(0);
    };

    #define BAR __builtin_amdgcn_s_barrier()
    #define LGKM0_FENCE do { \
        asm volatile("s_waitcnt lgkmcnt(0)" ::: "memory"); \
        __builtin_amdgcn_sched_barrier(0); } while (0)

    i32x8 afA[4];     // current A-half fragments (A0 in p1-p2, A1 in p3-p4)
    i32x8 bfr0[2];    // B-half0, held p1 -> p4
    i32x8 bfrB[2];    // B-half1

    // ---- prologue: stage K-window 0 (A0,B0,B1,A1); drain A0,B0 ----
    stageA(0, 0, 0); stageB(0, 0, 0); stageB(0, 1, 0); stageA(0, 1, 0);
    asm volatile("s_waitcnt vmcnt(4)" ::: "memory");
    BAR;

    // ---- main loop: windows t=0..2, staging window t+1 into buf^1 ----
    for (int t = 0; t < 3; ++t) {
        const int b = t & 1, nb = b ^ 1;

        // P1: quadrant (0,0) — 12 ds_reads, stage A0(t+1)
        ldA(afA, b, 0);
        ldB(bfr0, b, 0);
        stageA(nb, 0, t + 1);
        asm volatile("s_waitcnt vmcnt(4) lgkmcnt(8)" ::: "memory");  // drains B1(t)
        BAR;
        LGKM0_FENCE;
        mmaq(acc00, afA, bfr0);
        BAR;

        // P2: quadrant (0,1) — 4 ds_reads, stage B0(t+1)
        ldB(bfrB, b, 1);
        stageB(nb, 0, t + 1);
        asm volatile("s_waitcnt vmcnt(4)" ::: "memory");             // drains A1(t)
        BAR;
        LGKM0_FENCE;
        mmaq(acc01, afA, bfrB);
        BAR;

        // P3: quadrant (1,1) — 8 ds_reads, stage B1(t+1)
        ldA(afA, b, 1);
        stageB(nb, 1, t + 1);
        asm volatile("s_waitcnt vmcnt(4)" ::: "memory");             // drains A0(t+1)
        BAR;
        LGKM0_FENCE;
        mmaq(acc11, afA, bfrB);
        BAR;

        // P4: quadrant (1,0) — 0 ds_reads (B0 held), stage A1(t+1)
        stageA(nb, 1, t + 1);
        asm volatile("s_waitcnt vmcnt(4)" ::: "memory");             // drains B0(t+1)
        BAR;
        __builtin_amdgcn_sched_barrier(0);
        mmaq(acc10, afA, bfr0);
        BAR;
    }

    // ---- tail: window 3 in buf 1, no staging; drain 4 -> 2 -> 0 ----
    {
        ldA(afA, 1, 0);
        ldB(bfr0, 1, 0);
        asm volatile("s_waitcnt vmcnt(2)" ::: "memory");             // drains B1(3)
        BAR;
        LGKM0_FENCE;
        mmaq(acc00, afA, bfr0);
        BAR;

        ldB(bfrB, 1, 1);
        asm volatile("s_waitcnt vmcnt(0)" ::: "memory");             // drains A1(3)
        BAR;
        LGKM0_FENCE;
        mmaq(acc01, afA, bfrB);
        BAR;

        ldA(afA, 1, 1);
        LGKM0_FENCE;
        mmaq(acc11, afA, bfrB);
        mmaq(acc10, afA, bfr0);
    }

    // ---- fused epilogue: relu(1 - diag[col] + sc) + relu(1 - diag[row] + sc)
    // C/D 16x16: col = lane&15 (=frow), row = (lane>>4)*4 + reg (fc*4+r)
    float lsum = 0.f;
    const int rb0 = bm * 256 + wm * 64;
    const int cb0 = bn * 256 + wn * 32;
    auto sumq = [&](f32x4 (&ac)[4][2], int qm, int qn) {
        #pragma unroll
        for (int mi = 0; mi < 4; ++mi) {
            const int rowb = rb0 + qm * 128 + mi * 16 + fc * 4;
            float dr[4];
            #pragma unroll
            for (int r = 0; r < 4; ++r) dr[r] = diag[rowb + r];
            #pragma unroll
            for (int ni = 0; ni < 2; ++ni) {
                const int col = cb0 + qn * 128 + ni * 16 + frow;
                const float dc = diag[col];
                #pragma unroll
                for (int r = 0; r < 4; ++r) {
                    if (rowb + r != col) {
                        const float sc = ac[mi][ni][r];
                        lsum += fmaxf(0.f, 1.0f - dc + sc)
                              + fmaxf(0.f, 1.0f - dr[r] + sc);
                    }
                }
            }
        }
    };
    sumq(acc00, 0, 0); sumq(acc01, 0, 1); sumq(acc11, 1, 1); sumq(acc10, 1, 0);

    #pragma unroll
    for (int off = 32; off; off >>= 1) lsum += __shfl_down(lsum, off);

    float* part = (float*)&Asm[0][0];   // reuse LDS (all tile reads done)
    __syncthreads();
    if (l == 0) part[w] = lsum;
    __syncthreads();
    if (tid == 0) {
        float bs = 0.f;
        #pragma unroll
        for (int i = 0; i < 8; ++i) bs += part[i];
        atomicAdd(acc_out, (double)bs);
    }
}

__global__ void finalize_kernel(const double* __restrict__ acc, float* __restrict__ out)
{
    out[0] = (float)(acc[0] * (1.0 / (double)NR));
}

extern "C" void kernel_launch(void* const* d_in, const int* in_sizes, int n_in,
                              void* d_out, int out_size, void* d_ws, size_t ws_size,
                              hipStream_t stream)
{
    const float* im = (const float*)d_in[0];
    const float* s  = (const float*)d_in[1];

    char* ws = (char*)d_ws;
    unsigned char* im_q = (unsigned char*)ws;                                 // 4 MB
    unsigned char* s_q  = (unsigned char*)(ws + (size_t)NR * DIM);            // 4 MB
    float* diag         = (float*)(ws + (size_t)NR * DIM * 2);                // 32 KB
    double* acc         = (double*)(ws + (size_t)NR * DIM * 2 + NR * 4);      // 8 B

    normalize_kernel<<<NR, 256, 0, stream>>>(im, s, im_q, s_q, diag, acc);

    dim3 grid(NR / 256, NR / 256);
    gemm_loss_kernel<<<grid, 512, 0, stream>>>(im_q, s_q, diag, acc);

    finalize_kernel<<<1, 1, 0, stream>>>(acc, (float*)d_out);
}

// Round 8
// 82.336 us; speedup vs baseline: 3.5175x; 3.5175x over previous
//
#include <hip/hip_runtime.h>
#include <hip/hip_bf16.h>
#include <hip/hip_fp8.h>

#define NR 8192
#define DIM 512   // bytes per row in fp8 == elements

typedef __attribute__((ext_vector_type(2))) int   i32x2;
typedef __attribute__((ext_vector_type(4))) int   i32x4;
typedef __attribute__((ext_vector_type(4))) float f32x4;

__device__ static inline void gload_lds16(const void* g, void* l) {
    __builtin_amdgcn_global_load_lds(
        (const __attribute__((address_space(1))) void*)g,
        (__attribute__((address_space(3))) void*)l, 16, 0, 0);
}

__device__ static inline long pk64(int a, int b) {
    union { i32x2 v; long l; } u;
    u.v[0] = a; u.v[1] = b;
    return u.l;
}

// One block (256 threads) per row: |im|^2, |s|^2, im.s in one pass; write
// fp8(e4m3)-normalized rows in K-PERMUTED layout + exact fp32 diag.
// Permutation (within each 128-B K-window): orig k = j*32 + fc*8 + b  ->
// stored byte fc*32 + j*8 + b. Lane fc of the MFMA then reads its operands
// for MFMA j0,j1 (resp. j2,j3) as ONE contiguous 16-B ds_read_b128.
// Applied identically to A and B => dot products unchanged.
__global__ __launch_bounds__(256) void normalize_kernel(
    const float* __restrict__ im, const float* __restrict__ s,
    unsigned char* __restrict__ im_q, unsigned char* __restrict__ s_q,
    float* __restrict__ diag, double* __restrict__ acc)
{
    const int row = blockIdx.x;
    const int t = threadIdx.x;
    if (row == 0 && t == 0) acc[0] = 0.0;

    const float2* imr = (const float2*)(im + (size_t)row * DIM);
    const float2* sr  = (const float2*)(s  + (size_t)row * DIM);
    float2 iv = imr[t];
    float2 sv = sr[t];

    float sim = iv.x * iv.x + iv.y * iv.y;
    float sss = sv.x * sv.x + sv.y * sv.y;
    float sd  = iv.x * sv.x + iv.y * sv.y;

    #pragma unroll
    for (int off = 32; off; off >>= 1) {
        sim += __shfl_down(sim, off);
        sss += __shfl_down(sss, off);
        sd  += __shfl_down(sd, off);
    }

    __shared__ float red[3][4];
    const int wid = t >> 6, lane = t & 63;
    if (lane == 0) { red[0][wid] = sim; red[1][wid] = sss; red[2][wid] = sd; }
    __syncthreads();
    sim = red[0][0] + red[0][1] + red[0][2] + red[0][3];
    sss = red[1][0] + red[1][1] + red[1][2] + red[1][3];
    sd  = red[2][0] + red[2][1] + red[2][2] + red[2][3];

    const float ri = rsqrtf(sim);
    const float rs = rsqrtf(sss);
    if (t == 0) diag[row] = sd * ri * rs;

    __hip_fp8_e4m3 qa0(iv.x * ri), qa1(iv.y * ri);
    __hip_fp8_e4m3 qb0(sv.x * rs), qb1(sv.y * rs);
    unsigned short ua = (unsigned short)qa0.__x | ((unsigned short)qa1.__x << 8);
    unsigned short ub = (unsigned short)qb0.__x | ((unsigned short)qb1.__x << 8);

    // permuted byte position for k0 = 2t (k0,k0+1 share j,fc since b even)
    const int k0 = 2 * t;
    const int win = k0 >> 7, inrow = k0 & 127;
    const int jj = (inrow >> 5) & 3, fcp = (inrow >> 3) & 3, bb = inrow & 7;
    const int np = win * 128 + fcp * 32 + jj * 8 + bb;
    *(unsigned short*)(im_q + (size_t)row * DIM + np) = ua;
    *(unsigned short*)(s_q  + (size_t)row * DIM + np) = ub;
}

// 256x256 tile, fp8, BK=128 (4 K-windows), 8 waves (2M x 4N), double-buffered
// LDS 128 KiB ([buf][256 rows][128 B], XOR chunk swizzle — R3-verified
// staging/read pattern, 0 conflicts). 4 quadrant-phases per window, R3's
// vmcnt(4) ledger (each drain targets a half-tile staged 2+ phases earlier;
// never 0 in main loop). 32 x mfma_f32_16x16x32_fp8_fp8 per phase (i64
// operands from the K-permuted b128 reads; acc stays in AGPRs — no spills).
__global__ __launch_bounds__(512, 2) void gemm_loss_kernel(
    const unsigned char* __restrict__ A,
    const unsigned char* __restrict__ B,
    const float* __restrict__ diag,
    double* __restrict__ acc_out)
{
    __shared__ char Asm[2][32768];   // [buf][256 rows][128 B]
    __shared__ char Bsm[2][32768];

    const int tid  = threadIdx.x;
    const int l    = tid & 63;
    const int w    = tid >> 6;          // wave 0..7
    const int wm   = w >> 2;            // 0..1
    const int wn   = w & 3;             // 0..3
    const int bm = blockIdx.y, bn = blockIdx.x;

    const int lr = l >> 3;              // 0..7 row within 8-row group
    const int ls = l & 7;               // 0..7 16B slot
    const int csw = ls ^ lr;            // swizzled content chunk for staging

    const int frow = l & 15;            // fragment lane row (output row/col)
    const int fc   = l >> 4;            // 0..3 k-group

    const char* Agb = (const char*)A + (size_t)bm * 256 * DIM;
    const char* Bgb = (const char*)B + (size_t)bn * 256 * DIM;

    auto stageA = [&](int b, int h, int tt) {
        #pragma unroll
        for (int q = 0; q < 2; ++q) {
            const int rit = h * 128 + q * 64 + w * 8 + lr;
            gload_lds16(Agb + (size_t)rit * DIM + tt * 128 + csw * 16,
                        &Asm[b][(h * 128 + q * 64 + w * 8) * 128]);
        }
    };
    auto stageB = [&](int b, int h, int tt) {
        #pragma unroll
        for (int q = 0; q < 2; ++q) {
            const int rit = h * 128 + q * 64 + w * 8 + lr;
            gload_lds16(Bgb + (size_t)rit * DIM + tt * 128 + csw * 16,
                        &Bsm[b][(h * 128 + q * 64 + w * 8) * 128]);
        }
    };

    // fragment reads: lane fc reads slots {2fc, 2fc+1} (XOR-swizzled) of its
    // 16 rows. lo = {mfma j0|j1 operand}, hi = {j2|j3}.
    auto ldA = [&](i32x4 (&aL)[4], i32x4 (&aH)[4], int b, int qm) {
        #pragma unroll
        for (int mi = 0; mi < 4; ++mi) {
            const int row = qm * 128 + wm * 64 + mi * 16 + frow;
            const int off = row * 128 + (((fc << 5)) ^ ((row & 7) << 4));
            aL[mi] = *(const i32x4*)&Asm[b][off];
            aH[mi] = *(const i32x4*)&Asm[b][off ^ 16];
        }
    };
    auto ldB = [&](i32x4 (&bL)[2], i32x4 (&bH)[2], int b, int qn) {
        #pragma unroll
        for (int ni = 0; ni < 2; ++ni) {
            const int row = qn * 128 + wn * 32 + ni * 16 + frow;
            const int off = row * 128 + (((fc << 5)) ^ ((row & 7) << 4));
            bL[ni] = *(const i32x4*)&Bsm[b][off];
            bH[ni] = *(const i32x4*)&Bsm[b][off ^ 16];
        }
    };

    f32x4 acc00[4][2], acc01[4][2], acc11[4][2], acc10[4][2];
    f32x4 zero = {0.f, 0.f, 0.f, 0.f};
    #pragma unroll
    for (int mi = 0; mi < 4; ++mi)
        #pragma unroll
        for (int ni = 0; ni < 2; ++ni) {
            acc00[mi][ni] = zero; acc01[mi][ni] = zero;
            acc11[mi][ni] = zero; acc10[mi][ni] = zero;
        }

    // one quadrant x K=128: 4 j-slices x (4m x 2n) = 32 MFMAs
    auto mmaq = [&](f32x4 (&ac)[4][2], i32x4 (&aL)[4], i32x4 (&aH)[4],
                    i32x4 (&bL)[2], i32x4 (&bH)[2]) {
        __builtin_amdgcn_s_setprio(1);
        #pragma unroll
        for (int j = 0; j < 4; ++j) {
            long bv0 = (j < 2) ? pk64(bL[0][(j & 1) * 2], bL[0][(j & 1) * 2 + 1])
                               : pk64(bH[0][(j & 1) * 2], bH[0][(j & 1) * 2 + 1]);
            long bv1 = (j < 2) ? pk64(bL[1][(j & 1) * 2], bL[1][(j & 1) * 2 + 1])
                               : pk64(bH[1][(j & 1) * 2], bH[1][(j & 1) * 2 + 1]);
            #pragma unroll
            for (int mi = 0; mi < 4; ++mi) {
                long av = (j < 2) ? pk64(aL[mi][(j & 1) * 2], aL[mi][(j & 1) * 2 + 1])
                                  : pk64(aH[mi][(j & 1) * 2], aH[mi][(j & 1) * 2 + 1]);
                ac[mi][0] = __builtin_amdgcn_mfma_f32_16x16x32_fp8_fp8(
                    av, bv0, ac[mi][0], 0, 0, 0);
                ac[mi][1] = __builtin_amdgcn_mfma_f32_16x16x32_fp8_fp8(
                    av, bv1, ac[mi][1], 0, 0, 0);
            }
        }
        __builtin_amdgcn_s_setprio(0);
    };

    #define BAR __builtin_amdgcn_s_barrier()
    #define LGKM0_FENCE do { \
        asm volatile("s_waitcnt lgkmcnt(0)" ::: "memory"); \
        __builtin_amdgcn_sched_barrier(0); } while (0)

    i32x4 aL[4], aH[4];     // current A-half frags (A0 in p1-p2, A1 in p3-p4)
    i32x4 b0L[2], b0H[2];   // B-half0, held p1 -> p4
    i32x4 bBL[2], bBH[2];   // B-half1

    // ---- prologue: stage K-window 0 (A0,B0,B1,A1); drain A0,B0 ----
    stageA(0, 0, 0); stageB(0, 0, 0); stageB(0, 1, 0); stageA(0, 1, 0);
    asm volatile("s_waitcnt vmcnt(4)" ::: "memory");
    BAR;

    // ---- main loop: windows t=0..2, staging window t+1 into buf^1 ----
    for (int t = 0; t < 3; ++t) {
        const int b = t & 1, nb = b ^ 1;

        // P1: quadrant (0,0) — 12 ds_reads, stage A0(t+1)
        ldA(aL, aH, b, 0);
        ldB(b0L, b0H, b, 0);
        stageA(nb, 0, t + 1);
        asm volatile("s_waitcnt vmcnt(4) lgkmcnt(8)" ::: "memory");  // drains B1(t)
        BAR;
        LGKM0_FENCE;
        mmaq(acc00, aL, aH, b0L, b0H);
        BAR;

        // P2: quadrant (0,1) — 4 ds_reads, stage B0(t+1)
        ldB(bBL, bBH, b, 1);
        stageB(nb, 0, t + 1);
        asm volatile("s_waitcnt vmcnt(4)" ::: "memory");             // drains A1(t)
        BAR;
        LGKM0_FENCE;
        mmaq(acc01, aL, aH, bBL, bBH);
        BAR;

        // P3: quadrant (1,1) — 8 ds_reads, stage B1(t+1)
        ldA(aL, aH, b, 1);
        stageB(nb, 1, t + 1);
        asm volatile("s_waitcnt vmcnt(4)" ::: "memory");             // drains A0(t+1)
        BAR;
        LGKM0_FENCE;
        mmaq(acc11, aL, aH, bBL, bBH);
        BAR;

        // P4: quadrant (1,0) — 0 ds_reads (B0 held), stage A1(t+1)
        stageA(nb, 1, t + 1);
        asm volatile("s_waitcnt vmcnt(4)" ::: "memory");             // drains B0(t+1)
        BAR;
        __builtin_amdgcn_sched_barrier(0);
        mmaq(acc10, aL, aH, b0L, b0H);
        BAR;
    }

    // ---- tail: window 3 in buf 1, no staging; drain 4 -> 2 -> 0 ----
    {
        ldA(aL, aH, 1, 0);
        ldB(b0L, b0H, 1, 0);
        asm volatile("s_waitcnt vmcnt(2)" ::: "memory");             // drains B1(3)
        BAR;
        LGKM0_FENCE;
        mmaq(acc00, aL, aH, b0L, b0H);
        BAR;

        ldB(bBL, bBH, 1, 1);
        asm volatile("s_waitcnt vmcnt(0)" ::: "memory");             // drains A1(3)
        BAR;
        LGKM0_FENCE;
        mmaq(acc01, aL, aH, bBL, bBH);
        BAR;

        ldA(aL, aH, 1, 1);
        LGKM0_FENCE;
        mmaq(acc11, aL, aH, bBL, bBH);
        mmaq(acc10, aL, aH, b0L, b0H);
    }

    // ---- fused epilogue: relu(1 - diag[col] + sc) + relu(1 - diag[row] + sc)
    // C/D 16x16: col = lane&15 (=frow), row = (lane>>4)*4 + reg (fc*4+r)
    float lsum = 0.f;
    const int rb0 = bm * 256 + wm * 64;
    const int cb0 = bn * 256 + wn * 32;
    auto sumq = [&](f32x4 (&ac)[4][2], int qm, int qn) {
        #pragma unroll
        for (int mi = 0; mi < 4; ++mi) {
            const int rowb = rb0 + qm * 128 + mi * 16 + fc * 4;
            float dr[4];
            #pragma unroll
            for (int r = 0; r < 4; ++r) dr[r] = diag[rowb + r];
            #pragma unroll
            for (int ni = 0; ni < 2; ++ni) {
                const int col = cb0 + qn * 128 + ni * 16 + frow;
                const float dc = diag[col];
                #pragma unroll
                for (int r = 0; r < 4; ++r) {
                    if (rowb + r != col) {
                        const float sc = ac[mi][ni][r];
                        lsum += fmaxf(0.f, 1.0f - dc + sc)
                              + fmaxf(0.f, 1.0f - dr[r] + sc);
                    }
                }
            }
        }
    };
    sumq(acc00, 0, 0); sumq(acc01, 0, 1); sumq(acc11, 1, 1); sumq(acc10, 1, 0);

    #pragma unroll
    for (int off = 32; off; off >>= 1) lsum += __shfl_down(lsum, off);

    float* part = (float*)&Asm[0][0];   // reuse LDS (all tile reads done)
    __syncthreads();
    if (l == 0) part[w] = lsum;
    __syncthreads();
    if (tid == 0) {
        float bs = 0.f;
        #pragma unroll
        for (int i = 0; i < 8; ++i) bs += part[i];
        atomicAdd(acc_out, (double)bs);
    }
}

__global__ void finalize_kernel(const double* __restrict__ acc, float* __restrict__ out)
{
    out[0] = (float)(acc[0] * (1.0 / (double)NR));
}

extern "C" void kernel_launch(void* const* d_in, const int* in_sizes, int n_in,
                              void* d_out, int out_size, void* d_ws, size_t ws_size,
                              hipStream_t stream)
{
    const float* im = (const float*)d_in[0];
    const float* s  = (const float*)d_in[1];

    char* ws = (char*)d_ws;
    unsigned char* im_q = (unsigned char*)ws;                                 // 4 MB
    unsigned char* s_q  = (unsigned char*)(ws + (size_t)NR * DIM);            // 4 MB
    float* diag         = (float*)(ws + (size_t)NR * DIM * 2);                // 32 KB
    double* acc         = (double*)(ws + (size_t)NR * DIM * 2 + NR * 4);      // 8 B

    normalize_kernel<<<NR, 256, 0, stream>>>(im, s, im_q, s_q, diag, acc);

    dim3 grid(NR / 256, NR / 256);
    gemm_loss_kernel<<<grid, 512, 0, stream>>>(im_q, s_q, diag, acc);

    finalize_kernel<<<1, 1, 0, stream>>>(acc, (float*)d_out);
}

// Round 9
// 77.506 us; speedup vs baseline: 3.7367x; 1.0623x over previous
//
#include <hip/hip_runtime.h>
#include <hip/hip_bf16.h>
#include <hip/hip_fp8.h>

#define NR 8192
#define DIM 512   // bytes per row in fp8 == elements

typedef __attribute__((ext_vector_type(2))) int   i32x2;
typedef __attribute__((ext_vector_type(4))) int   i32x4;
typedef __attribute__((ext_vector_type(4))) float f32x4;

__device__ static inline void gload_lds16(const void* g, void* l) {
    __builtin_amdgcn_global_load_lds(
        (const __attribute__((address_space(1))) void*)g,
        (__attribute__((address_space(3))) void*)l, 16, 0, 0);
}

__device__ static inline long pk64(int a, int b) {
    union { i32x2 v; long l; } u;
    u.v[0] = a; u.v[1] = b;
    return u.l;
}

// One block (256 threads) per row: |im|^2, |s|^2, im.s in one pass; write
// fp8(e4m3)-normalized rows in K-PERMUTED layout + exact fp32 diag.
// Permutation (within each 128-B K-window): orig k (j=k>>5, fc=(k>>3)&3,
// b=k&7) -> stored byte fc*16 + (j>>1)*64 + (j&1)*8 + b. MFMA lane group fc
// then reads slot {fc} (j0,j1 operands) and slot {fc+4} (j2,j3) — the same
// consecutive-slot-set pattern R3 measured at 0 bank conflicts (R8's
// even/odd split slot sets cost 3.1M conflict cycles). Applied identically
// to A and B => dot products unchanged.
__global__ __launch_bounds__(256) void normalize_kernel(
    const float* __restrict__ im, const float* __restrict__ s,
    unsigned char* __restrict__ im_q, unsigned char* __restrict__ s_q,
    float* __restrict__ diag, double* __restrict__ acc)
{
    const int row = blockIdx.x;
    const int t = threadIdx.x;
    if (row == 0 && t == 0) acc[0] = 0.0;

    const float2* imr = (const float2*)(im + (size_t)row * DIM);
    const float2* sr  = (const float2*)(s  + (size_t)row * DIM);
    float2 iv = imr[t];
    float2 sv = sr[t];

    float sim = iv.x * iv.x + iv.y * iv.y;
    float sss = sv.x * sv.x + sv.y * sv.y;
    float sd  = iv.x * sv.x + iv.y * sv.y;

    #pragma unroll
    for (int off = 32; off; off >>= 1) {
        sim += __shfl_down(sim, off);
        sss += __shfl_down(sss, off);
        sd  += __shfl_down(sd, off);
    }

    __shared__ float red[3][4];
    const int wid = t >> 6, lane = t & 63;
    if (lane == 0) { red[0][wid] = sim; red[1][wid] = sss; red[2][wid] = sd; }
    __syncthreads();
    sim = red[0][0] + red[0][1] + red[0][2] + red[0][3];
    sss = red[1][0] + red[1][1] + red[1][2] + red[1][3];
    sd  = red[2][0] + red[2][1] + red[2][2] + red[2][3];

    const float ri = rsqrtf(sim);
    const float rs = rsqrtf(sss);
    if (t == 0) diag[row] = sd * ri * rs;

    __hip_fp8_e4m3 qa0(iv.x * ri), qa1(iv.y * ri);
    __hip_fp8_e4m3 qb0(sv.x * rs), qb1(sv.y * rs);
    unsigned short ua = (unsigned short)qa0.__x | ((unsigned short)qa1.__x << 8);
    unsigned short ub = (unsigned short)qb0.__x | ((unsigned short)qb1.__x << 8);

    // permuted byte position for k0 = 2t (k0,k0+1 share j,fc; b even)
    const int k0 = 2 * t;
    const int win = k0 >> 7, inrow = k0 & 127;
    const int jj = (inrow >> 5) & 3, fcp = (inrow >> 3) & 3, bb = inrow & 7;
    const int np = win * 128 + fcp * 16 + (jj >> 1) * 64 + (jj & 1) * 8 + bb;
    *(unsigned short*)(im_q + (size_t)row * DIM + np) = ua;
    *(unsigned short*)(s_q  + (size_t)row * DIM + np) = ub;
}

// 256x256 tile, fp8, BK=128 (4 K-windows), 8 waves (2M x 4N), double-buffered
// LDS 128 KiB ([buf][256 rows][128 B], XOR chunk swizzle — R3-verified
// staging/read pattern). 4 quadrant-phases per window, R3's vmcnt(4) ledger
// (each drain targets a half-tile staged 2+ phases earlier; never 0 in main
// loop). ONE barrier per phase (R8 had 2: the post-MFMA barrier is
// redundant — staging targets the opposite buffer, and a wave passing phase
// p's barrier implies all waves issued p-1's MFMAs, i.e. their ds_reads were
// serviced; WAR on buffer re-stage has >=4 intervening barriers).
__global__ __launch_bounds__(512, 2) void gemm_loss_kernel(
    const unsigned char* __restrict__ A,
    const unsigned char* __restrict__ B,
    const float* __restrict__ diag,
    double* __restrict__ acc_out)
{
    __shared__ char Asm[2][32768];   // [buf][256 rows][128 B]
    __shared__ char Bsm[2][32768];

    const int tid  = threadIdx.x;
    const int l    = tid & 63;
    const int w    = tid >> 6;          // wave 0..7
    const int wm   = w >> 2;            // 0..1
    const int wn   = w & 3;             // 0..3
    const int bm = blockIdx.y, bn = blockIdx.x;

    const int lr = l >> 3;              // 0..7 row within 8-row group
    const int ls = l & 7;               // 0..7 16B slot
    const int csw = ls ^ lr;            // swizzled content chunk for staging

    const int frow = l & 15;            // fragment lane row (output row/col)
    const int fc   = l >> 4;            // 0..3 k-group

    const char* Agb = (const char*)A + (size_t)bm * 256 * DIM;
    const char* Bgb = (const char*)B + (size_t)bn * 256 * DIM;

    auto stageA = [&](int b, int h, int tt) {
        #pragma unroll
        for (int q = 0; q < 2; ++q) {
            const int rit = h * 128 + q * 64 + w * 8 + lr;
            gload_lds16(Agb + (size_t)rit * DIM + tt * 128 + csw * 16,
                        &Asm[b][(h * 128 + q * 64 + w * 8) * 128]);
        }
    };
    auto stageB = [&](int b, int h, int tt) {
        #pragma unroll
        for (int q = 0; q < 2; ++q) {
            const int rit = h * 128 + q * 64 + w * 8 + lr;
            gload_lds16(Bgb + (size_t)rit * DIM + tt * 128 + csw * 16,
                        &Bsm[b][(h * 128 + q * 64 + w * 8) * 128]);
        }
    };

    // fragment reads: lane group fc reads slots {fc} and {fc+4}
    // (XOR-swizzled by row&7) of its 16 rows — R3's 0-conflict pattern.
    auto ldA = [&](i32x4 (&aL)[4], i32x4 (&aH)[4], int b, int qm) {
        #pragma unroll
        for (int mi = 0; mi < 4; ++mi) {
            const int row = qm * 128 + wm * 64 + mi * 16 + frow;
            const int rsw = (row & 7) << 4;
            aL[mi] = *(const i32x4*)&Asm[b][row * 128 + ((fc << 4) ^ rsw)];
            aH[mi] = *(const i32x4*)&Asm[b][row * 128 + (((fc + 4) << 4) ^ rsw)];
        }
    };
    auto ldB = [&](i32x4 (&bL)[2], i32x4 (&bH)[2], int b, int qn) {
        #pragma unroll
        for (int ni = 0; ni < 2; ++ni) {
            const int row = qn * 128 + wn * 32 + ni * 16 + frow;
            const int rsw = (row & 7) << 4;
            bL[ni] = *(const i32x4*)&Bsm[b][row * 128 + ((fc << 4) ^ rsw)];
            bH[ni] = *(const i32x4*)&Bsm[b][row * 128 + (((fc + 4) << 4) ^ rsw)];
        }
    };

    f32x4 acc00[4][2], acc01[4][2], acc11[4][2], acc10[4][2];
    f32x4 zero = {0.f, 0.f, 0.f, 0.f};
    #pragma unroll
    for (int mi = 0; mi < 4; ++mi)
        #pragma unroll
        for (int ni = 0; ni < 2; ++ni) {
            acc00[mi][ni] = zero; acc01[mi][ni] = zero;
            acc11[mi][ni] = zero; acc10[mi][ni] = zero;
        }

    // one quadrant x K=128: j-slices j0,j1 from lo regs, j2,j3 from hi regs
    auto mmaq = [&](f32x4 (&ac)[4][2], i32x4 (&aL)[4], i32x4 (&aH)[4],
                    i32x4 (&bL)[2], i32x4 (&bH)[2]) {
        __builtin_amdgcn_s_setprio(1);
        #pragma unroll
        for (int j = 0; j < 4; ++j) {
            long bv0 = (j < 2) ? pk64(bL[0][(j & 1) * 2], bL[0][(j & 1) * 2 + 1])
                               : pk64(bH[0][(j & 1) * 2], bH[0][(j & 1) * 2 + 1]);
            long bv1 = (j < 2) ? pk64(bL[1][(j & 1) * 2], bL[1][(j & 1) * 2 + 1])
                               : pk64(bH[1][(j & 1) * 2], bH[1][(j & 1) * 2 + 1]);
            #pragma unroll
            for (int mi = 0; mi < 4; ++mi) {
                long av = (j < 2) ? pk64(aL[mi][(j & 1) * 2], aL[mi][(j & 1) * 2 + 1])
                                  : pk64(aH[mi][(j & 1) * 2], aH[mi][(j & 1) * 2 + 1]);
                ac[mi][0] = __builtin_amdgcn_mfma_f32_16x16x32_fp8_fp8(
                    av, bv0, ac[mi][0], 0, 0, 0);
                ac[mi][1] = __builtin_amdgcn_mfma_f32_16x16x32_fp8_fp8(
                    av, bv1, ac[mi][1], 0, 0, 0);
            }
        }
        __builtin_amdgcn_s_setprio(0);
    };

    #define BAR __builtin_amdgcn_s_barrier()
    #define LGKM0_FENCE do { \
        asm volatile("s_waitcnt lgkmcnt(0)" ::: "memory"); \
        __builtin_amdgcn_sched_barrier(0); } while (0)

    i32x4 aL[4], aH[4];     // current A-half frags (A0 in p1-p2, A1 in p3-p4)
    i32x4 b0L[2], b0H[2];   // B-half0, held p1 -> p4
    i32x4 bBL[2], bBH[2];   // B-half1

    // ---- prologue: stage K-window 0 (A0,B0,B1,A1); drain A0,B0 ----
    stageA(0, 0, 0); stageB(0, 0, 0); stageB(0, 1, 0); stageA(0, 1, 0);
    asm volatile("s_waitcnt vmcnt(4)" ::: "memory");
    BAR;

    // ---- main loop: windows t=0..2, staging window t+1 into buf^1 ----
    for (int t = 0; t < 3; ++t) {
        const int b = t & 1, nb = b ^ 1;

        // P1: quadrant (0,0) — 12 ds_reads, stage A0(t+1)
        ldA(aL, aH, b, 0);
        ldB(b0L, b0H, b, 0);
        stageA(nb, 0, t + 1);
        asm volatile("s_waitcnt vmcnt(4) lgkmcnt(8)" ::: "memory");  // drains B1(t)
        BAR;
        LGKM0_FENCE;
        mmaq(acc00, aL, aH, b0L, b0H);

        // P2: quadrant (0,1) — 4 ds_reads, stage B0(t+1)
        ldB(bBL, bBH, b, 1);
        stageB(nb, 0, t + 1);
        asm volatile("s_waitcnt vmcnt(4)" ::: "memory");             // drains A1(t)
        BAR;
        LGKM0_FENCE;
        mmaq(acc01, aL, aH, bBL, bBH);

        // P3: quadrant (1,1) — 8 ds_reads, stage B1(t+1)
        ldA(aL, aH, b, 1);
        stageB(nb, 1, t + 1);
        asm volatile("s_waitcnt vmcnt(4)" ::: "memory");             // drains A0(t+1)
        BAR;
        LGKM0_FENCE;
        mmaq(acc11, aL, aH, bBL, bBH);

        // P4: quadrant (1,0) — 0 ds_reads (B0 held), stage A1(t+1)
        stageA(nb, 1, t + 1);
        asm volatile("s_waitcnt vmcnt(4)" ::: "memory");             // drains B0(t+1)
        BAR;
        __builtin_amdgcn_sched_barrier(0);
        mmaq(acc10, aL, aH, b0L, b0H);
    }

    // ---- tail: window 3 in buf 1, no staging; drain 4 -> 2 -> 0 ----
    {
        ldA(aL, aH, 1, 0);
        ldB(b0L, b0H, 1, 0);
        asm volatile("s_waitcnt vmcnt(2)" ::: "memory");             // drains B1(3)
        BAR;
        LGKM0_FENCE;
        mmaq(acc00, aL, aH, b0L, b0H);

        ldB(bBL, bBH, 1, 1);
        asm volatile("s_waitcnt vmcnt(0)" ::: "memory");             // drains A1(3)
        BAR;
        LGKM0_FENCE;
        mmaq(acc01, aL, aH, bBL, bBH);

        ldA(aL, aH, 1, 1);
        LGKM0_FENCE;
        mmaq(acc11, aL, aH, bBL, bBH);
        mmaq(acc10, aL, aH, b0L, b0H);
    }

    // ---- fused epilogue: relu(1 - diag[col] + sc) + relu(1 - diag[row] + sc)
    // C/D 16x16: col = lane&15 (=frow), row = (lane>>4)*4 + reg (fc*4+r)
    float lsum = 0.f;
    const int rb0 = bm * 256 + wm * 64;
    const int cb0 = bn * 256 + wn * 32;
    auto sumq = [&](f32x4 (&ac)[4][2], int qm, int qn) {
        #pragma unroll
        for (int mi = 0; mi < 4; ++mi) {
            const int rowb = rb0 + qm * 128 + mi * 16 + fc * 4;
            float dr[4];
            #pragma unroll
            for (int r = 0; r < 4; ++r) dr[r] = diag[rowb + r];
            #pragma unroll
            for (int ni = 0; ni < 2; ++ni) {
                const int col = cb0 + qn * 128 + ni * 16 + frow;
                const float dc = diag[col];
                #pragma unroll
                for (int r = 0; r < 4; ++r) {
                    if (rowb + r != col) {
                        const float sc = ac[mi][ni][r];
                        lsum += fmaxf(0.f, 1.0f - dc + sc)
                              + fmaxf(0.f, 1.0f - dr[r] + sc);
                    }
                }
            }
        }
    };
    sumq(acc00, 0, 0); sumq(acc01, 0, 1); sumq(acc11, 1, 1); sumq(acc10, 1, 0);

    #pragma unroll
    for (int off = 32; off; off >>= 1) lsum += __shfl_down(lsum, off);

    float* part = (float*)&Asm[0][0];   // reuse LDS (all tile reads done)
    __syncthreads();
    if (l == 0) part[w] = lsum;
    __syncthreads();
    if (tid == 0) {
        float bs = 0.f;
        #pragma unroll
        for (int i = 0; i < 8; ++i) bs += part[i];
        atomicAdd(acc_out, (double)bs);
    }
}

__global__ void finalize_kernel(const double* __restrict__ acc, float* __restrict__ out)
{
    out[0] = (float)(acc[0] * (1.0 / (double)NR));
}

extern "C" void kernel_launch(void* const* d_in, const int* in_sizes, int n_in,
                              void* d_out, int out_size, void* d_ws, size_t ws_size,
                              hipStream_t stream)
{
    const float* im = (const float*)d_in[0];
    const float* s  = (const float*)d_in[1];

    char* ws = (char*)d_ws;
    unsigned char* im_q = (unsigned char*)ws;                                 // 4 MB
    unsigned char* s_q  = (unsigned char*)(ws + (size_t)NR * DIM);            // 4 MB
    float* diag         = (float*)(ws + (size_t)NR * DIM * 2);                // 32 KB
    double* acc         = (double*)(ws + (size_t)NR * DIM * 2 + NR * 4);      // 8 B

    normalize_kernel<<<NR, 256, 0, stream>>>(im, s, im_q, s_q, diag, acc);

    dim3 grid(NR / 256, NR / 256);
    gemm_loss_kernel<<<grid, 512, 0, stream>>>(im_q, s_q, diag, acc);

    finalize_kernel<<<1, 1, 0, stream>>>(acc, (float*)d_out);
}